// Round 11
// baseline (405.998 us; speedup 1.0000x reference)
//
#include <hip/hip_runtime.h>
#include <hip/hip_bf16.h>

// Problem constants (match reference)
#define NUM_MIRNA 20000
#define NUM_GENE  30000
#define NN        50000      // total nodes
#define RR        4          // relations
#define EE        1000000    // edges
#define IN_C      128
#define HIDC      128
#define OUTC      64
#define NBASIS    10
#define NSEG      (RR * NN)  // 200000, seg = dst*4 + r
#define KFUSE     640        // 4*128 aggregated blocks + 128 root block
#define SROW      512        // S row length (bf16 cols) — root block read from x

#define NBKT   64            // dst-range buckets (49 used)
#define BSH    10            // bucket = dst >> 10
#define CHUNK  1024          // bs0/bs1 work per block
#define NCHUNK ((EE + CHUNK - 1) / CHUNK)   // 977
#define FCHUNK 4096          // fill2 work per block
#define CPB    7             // max 4096-chunks per bucket for fill2 grid

typedef __attribute__((ext_vector_type(8))) short bf16x8;
typedef __attribute__((ext_vector_type(4))) float f32x4;
typedef __attribute__((ext_vector_type(2))) float f32x2;

__device__ inline ushort f2bf(float x) {
    uint u = __float_as_uint(x);
    uint r = u + 0x7fffu + ((u >> 16) & 1u);
    return (ushort)(r >> 16);
}
__device__ inline float bf2f(ushort b) {
    return __uint_as_float((uint)b << 16);
}
__device__ inline uint pack2bf(float lo, float hi) {
    return (uint)f2bf(lo) | ((uint)f2bf(hi) << 16);
}
__device__ inline f32x2 up2(uint u) {   // unpack 2 bf16 -> f32x2 (lo, hi)
    return (f32x2){__uint_as_float(u << 16), __uint_as_float(u & 0xffff0000u)};
}

// async global->LDS, 16 bytes per lane (wave-linear LDS dest)
#define GLOAD_LDS16(gsrc, ldst)                                                \
    __builtin_amdgcn_global_load_lds(                                          \
        (const __attribute__((address_space(1))) void*)(gsrc),                 \
        (__attribute__((address_space(3))) void*)(ldst), 16, 0, 0)

// ---------------------------------------------------------------------------
// fp32 -> bf16 (4 elems/thread)
__global__ void cvt_k(const float* __restrict__ in, ushort* __restrict__ out, int n4) {
    int i = blockIdx.x * 256 + threadIdx.x;
    if (i >= n4) return;
    float4 v = ((const float4*)in)[i];
    ushort4 o;
    o.x = f2bf(v.x); o.y = f2bf(v.y); o.z = f2bf(v.z); o.w = f2bf(v.w);
    ((ushort4*)out)[i] = o;
}

// transpose+cast: Wt[o][k] = bf16(W[k][o]);  W: [K][OC]  (input projections)
__global__ void tcast_k(const float* __restrict__ W, ushort* __restrict__ Wt,
                        int K, int OC) {
    int idx = blockIdx.x * 256 + threadIdx.x;
    if (idx >= K * OC) return;
    int o = idx / K, k = idx % K;
    Wt[idx] = f2bf(W[(size_t)k * OC + o]);
}

// Build stacked transposed fused weight: Wt[o][k], k in [0,640)
__global__ void buildW_k(const float* __restrict__ comp, const float* __restrict__ basis,
                         const float* __restrict__ root, ushort* __restrict__ Wt, int O) {
    int idx = blockIdx.x * 256 + threadIdx.x;
    if (idx >= O * KFUSE) return;
    int o = idx / KFUSE, k = idx % KFUSE;
    float acc;
    if (k < 512) {
        int r = k >> 7, i = k & 127;
        acc = 0.f;
#pragma unroll
        for (int b = 0; b < NBASIS; ++b)
            acc += comp[r * NBASIS + b] * basis[((size_t)b * 128 + i) * O + o];
    } else {
        acc = root[(size_t)(k - 512) * O + o];
    }
    Wt[idx] = f2bf(acc);
}

// ---------------------------------------------------------------------------
// Staged MFMA bf16 GEMM: C[M][OC] = A[M][K] @ Wt[OC][K]^T (+bias)
// 2-phase double-buffered LDS pipeline with global_load_lds + XOR swizzle.
template <int NT, int K, bool OUT_BF16, bool ROOTX>
__global__ __launch_bounds__(256) void sgemm_k(
    const ushort* __restrict__ A, const ushort* __restrict__ xroot,
    const ushort* __restrict__ Wt, const float* __restrict__ bias,
    void* __restrict__ Cout, int M)
{
    constexpr int OC = 2 * NT * 16;
    constexpr int BK = 64;
    constexpr int NTILE = K / BK;
    constexpr int AS = ROOTX ? SROW : K;

    __shared__ __align__(16) ushort As[2 * 4096];   // 2 x (64x64) bf16 = 16KB

    const int tid  = threadIdx.x;
    const int lane = tid & 63;
    const int wid  = tid >> 6;
    const int wm   = wid >> 1;
    const int wn   = wid & 1;
    const int l15  = lane & 15;
    const int lg   = lane >> 4;
    const int rowBase = blockIdx.x * 64;
    const int colBase = wn * NT * 16;

    f32x4 acc[2][NT];
#pragma unroll
    for (int mt = 0; mt < 2; ++mt)
#pragma unroll
        for (int nt = 0; nt < NT; ++nt)
            acc[mt][nt] = (f32x4){0.f, 0.f, 0.f, 0.f};

    auto STAGE = [&](int buf, int t) {
        const int kc = t * BK;
#pragma unroll
        for (int i = 0; i < 2; ++i) {
            int L   = i * 4096 + tid * 16;      // byte offset within 8KB tile
            int row = L >> 7;                    // 0..63
            int bs  = (L & 127) ^ ((row & 7) << 4);  // pre-swizzled src byte
            int grow = rowBase + row; if (grow >= M) grow = M - 1;
            const ushort* src;
            if (!ROOTX || kc < SROW)
                src = A + (size_t)grow * AS + kc + (bs >> 1);
            else
                src = xroot + (size_t)grow * IN_C + (kc - SROW) + (bs >> 1);
            GLOAD_LDS16(src, &As[(size_t)buf * 4096 + (L >> 1)]);
        }
    };

    STAGE(0, 0);
    __syncthreads();

#pragma unroll
    for (int t = 0; t < NTILE; ++t) {
        const int kc  = t * BK;
        const int buf = t & 1;

        // B fragments first (so vmcnt wait on B doesn't drain the stage)
        bf16x8 bB[2][NT];
#pragma unroll
        for (int kk = 0; kk < 2; ++kk)
#pragma unroll
            for (int nt = 0; nt < NT; ++nt)
                bB[kk][nt] = *(const bf16x8*)(
                    Wt + (size_t)(colBase + nt * 16 + l15) * K + kc + kk * 32 + lg * 8);

        // prefetch next tile into the other buffer
        if (t + 1 < NTILE) STAGE(buf ^ 1, t + 1);

        // A fragments from LDS (swizzled read)
        bf16x8 aF[2][2];
#pragma unroll
        for (int mt = 0; mt < 2; ++mt)
#pragma unroll
            for (int kk = 0; kk < 2; ++kk) {
                int row = wm * 32 + mt * 16 + l15;
                int kb  = kk * 64 + lg * 16;
                aF[mt][kk] = *(const bf16x8*)&As[
                    (size_t)buf * 4096 + row * 64 + ((kb ^ ((row & 7) << 4)) >> 1)];
            }

#pragma unroll
        for (int kk = 0; kk < 2; ++kk)
#pragma unroll
            for (int nt = 0; nt < NT; ++nt)
#pragma unroll
                for (int mt = 0; mt < 2; ++mt)
                    acc[mt][nt] = __builtin_amdgcn_mfma_f32_16x16x32_bf16(
                        aF[mt][kk], bB[kk][nt], acc[mt][nt], 0, 0, 0);

        __syncthreads();
    }

#pragma unroll
    for (int nt = 0; nt < NT; ++nt) {
        int n = colBase + nt * 16 + l15;
        float bv = bias ? bias[n] : 0.f;
#pragma unroll
        for (int mt = 0; mt < 2; ++mt) {
#pragma unroll
            for (int q = 0; q < 4; ++q) {
                int m = rowBase + wm * 32 + mt * 16 + lg * 4 + q;
                if (m < M) {
                    float v = acc[mt][nt][q] + bv;
                    size_t off = (size_t)m * OC + n;
                    if (OUT_BF16) ((ushort*)Cout)[off] = f2bf(v);
                    else          ((float*)Cout)[off]  = v;
                }
            }
        }
    }
}

// ---------------------------------------------------------------------------
// Bucketed CSR build.
__global__ __launch_bounds__(256) void bs0_k(const int* __restrict__ dstA,
                                             int* __restrict__ bcnt) {
    __shared__ int h[NBKT];
    int t = threadIdx.x;
    if (t < NBKT) h[t] = 0;
    __syncthreads();
    int e0 = blockIdx.x * CHUNK;
    int n = EE - e0; if (n > CHUNK) n = CHUNK;
    for (int i = t; i < n; i += 256)
        atomicAdd(&h[dstA[e0 + i] >> BSH], 1);
    __syncthreads();
    if (t < NBKT && h[t]) atomicAdd(&bcnt[t], h[t]);
}

__global__ void bscan_k(const int* __restrict__ bcnt, int* __restrict__ bbase,
                        int* __restrict__ bcur) {
    if (threadIdx.x == 0) {
        int run = 0;
        for (int i = 0; i < NBKT; ++i) { bbase[i] = run; bcur[i] = run; run += bcnt[i]; }
    }
}

// bs1: multi-split into bucket-contiguous (src,seg) + fused per-seg count.
// No LDS edge staging (re-read coalesced, L2-hot); LDS = 3 x 256B -> high occ.
__global__ __launch_bounds__(256) void bs1_k(const int* __restrict__ srcA,
                                             const int* __restrict__ dstA,
                                             const int* __restrict__ et,
                                             int* __restrict__ bcur,
                                             int* __restrict__ bsrc,
                                             int* __restrict__ bseg,
                                             int* __restrict__ cnt) {
    __shared__ int h[NBKT], cur[NBKT], boff[NBKT];
    int t = threadIdx.x;
    if (t < NBKT) h[t] = 0;
    __syncthreads();
    int e0 = blockIdx.x * CHUNK;
    int n = EE - e0; if (n > CHUNK) n = CHUNK;
    for (int i = t; i < n; i += 256)
        atomicAdd(&h[dstA[e0 + i] >> BSH], 1);
    __syncthreads();
    if (t < NBKT) {
        boff[t] = h[t] ? atomicAdd(&bcur[t], h[t]) : 0;
        cur[t] = 0;
    }
    __syncthreads();
    for (int i = t; i < n; i += 256) {
        int e = e0 + i;
        int d = dstA[e];
        int s2 = d * 4 + et[e];
        int b = d >> BSH;
        int slot = atomicAdd(&cur[b], 1);
        int pos = boff[b] + slot;
        bsrc[pos] = srcA[e];
        bseg[pos] = s2;
        atomicAdd(&cnt[s2], 1);
    }
}

// ---------------------------------------------------------------------------
// Segment-offset scan (counts -> exclusive base)
#define SCAN_B 256
#define SCAN_I 8
#define SCAN_T (SCAN_B * SCAN_I)   // 2048 elems per block

__global__ void scan1_k(const int* __restrict__ in, int* __restrict__ out,
                        int* __restrict__ bsum, int n) {
    __shared__ int sm[SCAN_B];
    int b = blockIdx.x;
    int t = threadIdx.x;
    int basei = b * SCAN_T + t * SCAN_I;
    int v[SCAN_I]; int s = 0;
#pragma unroll
    for (int i = 0; i < SCAN_I; ++i) {
        int idx = basei + i;
        v[i] = (idx < n) ? in[idx] : 0;
        s += v[i];
    }
    sm[t] = s; __syncthreads();
    for (int off = 1; off < SCAN_B; off <<= 1) {
        int x = (t >= off) ? sm[t - off] : 0;
        __syncthreads();
        sm[t] += x;
        __syncthreads();
    }
    int run = (t > 0) ? sm[t - 1] : 0;
    if (t == SCAN_B - 1) bsum[b] = sm[t];
#pragma unroll
    for (int i = 0; i < SCAN_I; ++i) {
        int idx = basei + i;
        if (idx < n) out[idx] = run;
        run += v[i];
    }
}

__global__ void scan2_k(int* __restrict__ bsum, int nb) {
    __shared__ int sm[256];
    int t = threadIdx.x;
    int v = (t < nb) ? bsum[t] : 0;
    sm[t] = v; __syncthreads();
    for (int off = 1; off < 256; off <<= 1) {
        int x = (t >= off) ? sm[t - off] : 0;
        __syncthreads();
        sm[t] += x;
        __syncthreads();
    }
    if (t < nb) bsum[t] = sm[t] - v;
}

__global__ void scan3inv_k(int* __restrict__ base, const int* __restrict__ bsum,
                           const int* __restrict__ cnt, float* __restrict__ inv,
                           int* __restrict__ cursor, int n) {
    int i = blockIdx.x * 256 + threadIdx.x;
    if (i < n) {
        int b = base[i] + bsum[i / SCAN_T];
        base[i] = b;
        cursor[i] = b;
        inv[i] = 1.0f / fmaxf((float)cnt[i], 1.0f);
    }
}

__global__ __launch_bounds__(256) void fill2_k(const int* __restrict__ bsrc,
                                               const int* __restrict__ bseg,
                                               const int* __restrict__ bbase,
                                               const int* __restrict__ bcnt,
                                               int* __restrict__ cursor,
                                               int* __restrict__ sorted) {
    int b   = blockIdx.x & (NBKT - 1);
    int cwb = blockIdx.x >> 6;
    int s = bbase[b] + cwb * FCHUNK;
    int e = bbase[b] + bcnt[b];
    if (e > s + FCHUNK) e = s + FCHUNK;
    for (int i = s + (int)threadIdx.x; i < e; i += 256) {
        int seg = bseg[i];
        int pos = atomicAdd(&cursor[seg], 1);
        sorted[pos] = bsrc[i];
    }
}

// ---------------------------------------------------------------------------
// Aggregate x rows per (relation, dst) into S (bf16, SROW=512 cols):
// S[d][r*128+c] = inv[d*4+r] * sum_{e in seg(d,r)} x[src_e][c]
// One wave per dst; 4 relations advance in lockstep; 2-stage register
// pipeline (vc/vn statically named) so next step's 4 row loads are in
// flight during current step's accumulate.
__global__ __launch_bounds__(256) void gatherS_k(
    const ushort* __restrict__ x, const int* __restrict__ sorted,
    const int* __restrict__ base, const int* __restrict__ cnt,
    const float* __restrict__ inv, ushort* __restrict__ S)
{
    int d = (blockIdx.x * 256 + threadIdx.x) >> 6;
    int lane = threadIdx.x & 63;
    if (d >= NN) return;
    const uint4* xp = (const uint4*)x;   // 16 uint4 per 128-col row
    uint4* Sp = (uint4*)S;               // 64 uint4 per 512-col row
    const int slot = lane >> 4;          // 0..3
    const int cg   = lane & 15;          // uint4 index within row

    int4   b4 = ((const int4*)base)[d];
    int4   c4 = ((const int4*)cnt)[d];
    float4 w4 = ((const float4*)inv)[d];
    const int off[4]  = {0, b4.y - b4.x, b4.z - b4.x, b4.w - b4.x};
    const int cnts[4] = {c4.x, c4.y, c4.z, c4.w};
    const float wts[4] = {w4.x, w4.y, w4.z, w4.w};
    const int tot = (b4.w + c4.w) - b4.x;

    f32x2 acc[4][4];
#pragma unroll
    for (int r = 0; r < 4; ++r)
#pragma unroll
        for (int t = 0; t < 4; ++t) acc[r][t] = (f32x2){0.f, 0.f};

    if (tot <= 64) {
        int idx = 0;
        if (lane < tot) idx = sorted[b4.x + lane];
        int maxn = max(max(cnts[0], cnts[1]), max(cnts[2], cnts[3]));

        uint4 vc[4], vn[4];
        auto LOADJ = [&](int j, uint4* vv) {
            int e = j + slot;
#pragma unroll
            for (int r = 0; r < 4; ++r) {
                int src = __shfl(idx, off[r] + e);
                if (e < cnts[r] && j < maxn)
                    vv[r] = xp[(size_t)src * 16 + cg];
                else
                    vv[r] = (uint4){0u, 0u, 0u, 0u};
            }
        };
        auto ACCJ = [&](uint4* vv) {
#pragma unroll
            for (int r = 0; r < 4; ++r) {
                acc[r][0] += up2(vv[r].x);
                acc[r][1] += up2(vv[r].y);
                acc[r][2] += up2(vv[r].z);
                acc[r][3] += up2(vv[r].w);
            }
        };

        LOADJ(0, vc);
        for (int j = 0; j < maxn; j += 8) {
            LOADJ(j + 4, vn);   // in flight during ACCJ(vc)
            ACCJ(vc);
            LOADJ(j + 8, vc);   // in flight during ACCJ(vn)
            ACCJ(vn);
        }
    } else {
        // rare fallback: per-segment chunked processing
#pragma unroll
        for (int r = 0; r < 4; ++r) {
            int s0 = b4.x + off[r];
            int s1 = s0 + cnts[r];
            for (int i0 = s0; i0 < s1; i0 += 64) {
                int n = s1 - i0; if (n > 64) n = 64;
                int idx = 0;
                if (lane < n) idx = sorted[i0 + lane];
                for (int j = 0; j < n; j += 4) {
                    int e = j + slot;
                    int src = __shfl(idx, e);
                    if (e < n) {
                        uint4 v = xp[(size_t)src * 16 + cg];
                        acc[r][0] += up2(v.x);
                        acc[r][1] += up2(v.y);
                        acc[r][2] += up2(v.z);
                        acc[r][3] += up2(v.w);
                    }
                }
            }
        }
    }

#pragma unroll
    for (int r = 0; r < 4; ++r) {
        float wt = wts[r];
#pragma unroll
        for (int t = 0; t < 4; ++t) {
            acc[r][t].x += __shfl_xor(acc[r][t].x, 16);
            acc[r][t].y += __shfl_xor(acc[r][t].y, 16);
            acc[r][t].x += __shfl_xor(acc[r][t].x, 32);
            acc[r][t].y += __shfl_xor(acc[r][t].y, 32);
        }
        if (slot == 0) {
            uint4 o;
            o.x = pack2bf(acc[r][0].x * wt, acc[r][0].y * wt);
            o.y = pack2bf(acc[r][1].x * wt, acc[r][1].y * wt);
            o.z = pack2bf(acc[r][2].x * wt, acc[r][2].y * wt);
            o.w = pack2bf(acc[r][3].x * wt, acc[r][3].y * wt);
            Sp[(size_t)d * 64 + r * 16 + cg] = o;
        }
    }
}

// ---------------------------------------------------------------------------
extern "C" void kernel_launch(void* const* d_in, const int* in_sizes, int n_in,
                              void* d_out, int out_size, void* d_ws, size_t ws_size,
                              hipStream_t stream) {
    const float* x_mirna = (const float*)d_in[0];
    const float* x_gene  = (const float*)d_in[1];
    const int*   eidx    = (const int*)d_in[2];
    const int*   etype   = (const int*)d_in[3];
    const float* lin_w_m = (const float*)d_in[4];
    const float* lin_b_m = (const float*)d_in[5];
    const float* lin_w_g = (const float*)d_in[6];
    const float* lin_b_g = (const float*)d_in[7];
    const float* comp1   = (const float*)d_in[8];
    const float* basis1  = (const float*)d_in[9];
    const float* root1   = (const float*)d_in[10];
    const float* bias1   = (const float*)d_in[11];
    const float* comp2   = (const float*)d_in[12];
    const float* basis2  = (const float*)d_in[13];
    const float* root2   = (const float*)d_in[14];
    const float* bias2   = (const float*)d_in[15];

    const int* srcA = eidx;
    const int* dstA = eidx + EE;

    // workspace layout (bytes)
    char* p = (char*)d_ws;
    ushort* xmbf = (ushort*)p; p += (size_t)NUM_MIRNA * 256 * 2;
    ushort* xgbf = (ushort*)p; p += (size_t)NUM_GENE * 512 * 2;
    ushort* x0bf = (ushort*)p; p += (size_t)NN * IN_C * 2;
    ushort* x1bf = (ushort*)p; p += (size_t)NN * HIDC * 2;
    ushort* S    = (ushort*)p; p += (size_t)NN * SROW * 2;      // 51.2 MB
    ushort* Wtm  = (ushort*)p; p += (size_t)IN_C * 256 * 2;
    ushort* Wtg  = (ushort*)p; p += (size_t)IN_C * 512 * 2;
    ushort* Wt1s = (ushort*)p; p += (size_t)HIDC * KFUSE * 2;
    ushort* Wt2s = (ushort*)p; p += (size_t)OUTC * KFUSE * 2;
    float* inv   = (float*)p;  p += (size_t)NSEG * 4;
    int* cnt     = (int*)p;    p += (size_t)NSEG * 4;
    int* bcnt    = (int*)p;    p += NBKT * 4;                   // adjacent to cnt
    int* base    = (int*)p;    p += (size_t)NSEG * 4;
    int* cursor  = (int*)p;    p += (size_t)NSEG * 4;
    int* bsum    = (int*)p;    p += 1024;
    int* bbase   = (int*)p;    p += NBKT * 4;
    int* bcur    = (int*)p;    p += NBKT * 4;
    int* sorted  = (int*)p;    p += (size_t)EE * 4;
    int* bsrc    = (int*)p;    p += (size_t)EE * 4;
    int* bseg    = (int*)p;    p += (size_t)EE * 4;

    float* outp = (float*)d_out;

    hipMemsetAsync(cnt, 0, (size_t)(NSEG + NBKT) * sizeof(int), stream);

    // bf16 converts of inputs
    cvt_k<<<(NUM_MIRNA * 256 / 4 + 255) / 256, 256, 0, stream>>>(x_mirna, xmbf, NUM_MIRNA * 256 / 4);
    cvt_k<<<(NUM_GENE * 512 / 4 + 255) / 256, 256, 0, stream>>>(x_gene, xgbf, NUM_GENE * 512 / 4);

    // packed transposed weights
    tcast_k<<<(256 * IN_C + 255) / 256, 256, 0, stream>>>(lin_w_m, Wtm, 256, IN_C);
    tcast_k<<<(512 * IN_C + 255) / 256, 256, 0, stream>>>(lin_w_g, Wtg, 512, IN_C);
    buildW_k<<<(HIDC * KFUSE + 255) / 256, 256, 0, stream>>>(comp1, basis1, root1, Wt1s, HIDC);
    buildW_k<<<(OUTC * KFUSE + 255) / 256, 256, 0, stream>>>(comp2, basis2, root2, Wt2s, OUTC);

    // bucketed CSR build
    bs0_k<<<NCHUNK, 256, 0, stream>>>(dstA, bcnt);
    bscan_k<<<1, 64, 0, stream>>>(bcnt, bbase, bcur);
    bs1_k<<<NCHUNK, 256, 0, stream>>>(srcA, dstA, etype, bcur, bsrc, bseg, cnt);
    int nb = (NSEG + SCAN_T - 1) / SCAN_T;
    scan1_k<<<nb, SCAN_B, 0, stream>>>(cnt, base, bsum, NSEG);
    scan2_k<<<1, 256, 0, stream>>>(bsum, nb);
    scan3inv_k<<<(NSEG + 255) / 256, 256, 0, stream>>>(base, bsum, cnt, inv, cursor, NSEG);
    fill2_k<<<NBKT * CPB, 256, 0, stream>>>(bsrc, bseg, bbase, bcnt, cursor, sorted);

    // input projections -> x0bf (staged GEMMs, bf16 A)
    sgemm_k<4, 256, true, false><<<dim3((NUM_MIRNA + 63) / 64), 256, 0, stream>>>(
        xmbf, nullptr, Wtm, lin_b_m, x0bf, NUM_MIRNA);
    sgemm_k<4, 512, true, false><<<dim3((NUM_GENE + 63) / 64), 256, 0, stream>>>(
        xgbf, nullptr, Wtg, lin_b_g, x0bf + (size_t)NUM_MIRNA * IN_C, NUM_GENE);

    // layer 1: aggregate x0 -> S, then fused [rel GEMMs + root + bias]
    gatherS_k<<<(NN * 64 + 255) / 256, 256, 0, stream>>>(x0bf, sorted, base, cnt, inv, S);
    sgemm_k<4, KFUSE, true, true><<<dim3((NN + 63) / 64), 256, 0, stream>>>(
        S, x0bf, Wt1s, bias1, x1bf, NN);

    // layer 2: aggregate x1 -> S, fused GEMM -> out (fp32)
    gatherS_k<<<(NN * 64 + 255) / 256, 256, 0, stream>>>(x1bf, sorted, base, cnt, inv, S);
    sgemm_k<2, KFUSE, false, true><<<dim3((NN + 63) / 64), 256, 0, stream>>>(
        S, x1bf, Wt2s, bias2, outp, NN);
}

// Round 12
// 365.666 us; speedup vs baseline: 1.1103x; 1.1103x over previous
//
#include <hip/hip_runtime.h>
#include <hip/hip_bf16.h>

// Problem constants (match reference)
#define NUM_MIRNA 20000
#define NUM_GENE  30000
#define NN        50000      // total nodes
#define RR        4          // relations
#define EE        1000000    // edges
#define IN_C      128
#define HIDC      128
#define OUTC      64
#define NBASIS    10
#define NSEG      (RR * NN)  // 200000, seg = dst*4 + r
#define KFUSE     640        // 4*128 aggregated blocks + 128 root block
#define SROW      512        // S row length (bf16 cols) — root block read from x

#define NBKT   64            // dst-range buckets (49 used)
#define BSH    10            // bucket = dst >> 10
#define CHUNK  2048          // bs0/bs1 work per block -> 489 blocks, 17KB LDS
#define NCHUNK ((EE + CHUNK - 1) / CHUNK)   // 489
#define FCHUNK 4096          // fill2 work per block
#define CPB    7             // max 4096-chunks per bucket for fill2 grid

typedef __attribute__((ext_vector_type(8))) short bf16x8;
typedef __attribute__((ext_vector_type(4))) float f32x4;
typedef __attribute__((ext_vector_type(2))) float f32x2;

__device__ inline ushort f2bf(float x) {
    uint u = __float_as_uint(x);
    uint r = u + 0x7fffu + ((u >> 16) & 1u);
    return (ushort)(r >> 16);
}
__device__ inline float bf2f(ushort b) {
    return __uint_as_float((uint)b << 16);
}
__device__ inline uint pack2bf(float lo, float hi) {
    return (uint)f2bf(lo) | ((uint)f2bf(hi) << 16);
}
__device__ inline f32x2 up2(uint u) {   // unpack 2 bf16 -> f32x2 (lo, hi)
    return (f32x2){__uint_as_float(u << 16), __uint_as_float(u & 0xffff0000u)};
}

// async global->LDS, 16 bytes per lane (wave-linear LDS dest)
#define GLOAD_LDS16(gsrc, ldst)                                                \
    __builtin_amdgcn_global_load_lds(                                          \
        (const __attribute__((address_space(1))) void*)(gsrc),                 \
        (__attribute__((address_space(3))) void*)(ldst), 16, 0, 0)

// ---------------------------------------------------------------------------
// fp32 -> bf16 (4 elems/thread)
__global__ void cvt_k(const float* __restrict__ in, ushort* __restrict__ out, int n4) {
    int i = blockIdx.x * 256 + threadIdx.x;
    if (i >= n4) return;
    float4 v = ((const float4*)in)[i];
    ushort4 o;
    o.x = f2bf(v.x); o.y = f2bf(v.y); o.z = f2bf(v.z); o.w = f2bf(v.w);
    ((ushort4*)out)[i] = o;
}

// transpose+cast: Wt[o][k] = bf16(W[k][o]);  W: [K][OC]  (input projections)
__global__ void tcast_k(const float* __restrict__ W, ushort* __restrict__ Wt,
                        int K, int OC) {
    int idx = blockIdx.x * 256 + threadIdx.x;
    if (idx >= K * OC) return;
    int o = idx / K, k = idx % K;
    Wt[idx] = f2bf(W[(size_t)k * OC + o]);
}

// Build stacked transposed fused weight: Wt[o][k], k in [0,640)
__global__ void buildW_k(const float* __restrict__ comp, const float* __restrict__ basis,
                         const float* __restrict__ root, ushort* __restrict__ Wt, int O) {
    int idx = blockIdx.x * 256 + threadIdx.x;
    if (idx >= O * KFUSE) return;
    int o = idx / KFUSE, k = idx % KFUSE;
    float acc;
    if (k < 512) {
        int r = k >> 7, i = k & 127;
        acc = 0.f;
#pragma unroll
        for (int b = 0; b < NBASIS; ++b)
            acc += comp[r * NBASIS + b] * basis[((size_t)b * 128 + i) * O + o];
    } else {
        acc = root[(size_t)(k - 512) * O + o];
    }
    Wt[idx] = f2bf(acc);
}

// ---------------------------------------------------------------------------
// Staged MFMA bf16 GEMM: C[M][OC] = A[M][K] @ Wt[OC][K]^T (+bias)
// 2-phase double-buffered LDS pipeline with global_load_lds + XOR swizzle.
template <int NT, int K, bool OUT_BF16, bool ROOTX>
__global__ __launch_bounds__(256) void sgemm_k(
    const ushort* __restrict__ A, const ushort* __restrict__ xroot,
    const ushort* __restrict__ Wt, const float* __restrict__ bias,
    void* __restrict__ Cout, int M)
{
    constexpr int OC = 2 * NT * 16;
    constexpr int BK = 64;
    constexpr int NTILE = K / BK;
    constexpr int AS = ROOTX ? SROW : K;

    __shared__ __align__(16) ushort As[2 * 4096];   // 2 x (64x64) bf16 = 16KB

    const int tid  = threadIdx.x;
    const int lane = tid & 63;
    const int wid  = tid >> 6;
    const int wm   = wid >> 1;
    const int wn   = wid & 1;
    const int l15  = lane & 15;
    const int lg   = lane >> 4;
    const int rowBase = blockIdx.x * 64;
    const int colBase = wn * NT * 16;

    f32x4 acc[2][NT];
#pragma unroll
    for (int mt = 0; mt < 2; ++mt)
#pragma unroll
        for (int nt = 0; nt < NT; ++nt)
            acc[mt][nt] = (f32x4){0.f, 0.f, 0.f, 0.f};

    auto STAGE = [&](int buf, int t) {
        const int kc = t * BK;
#pragma unroll
        for (int i = 0; i < 2; ++i) {
            int L   = i * 4096 + tid * 16;      // byte offset within 8KB tile
            int row = L >> 7;                    // 0..63
            int bs  = (L & 127) ^ ((row & 7) << 4);  // pre-swizzled src byte
            int grow = rowBase + row; if (grow >= M) grow = M - 1;
            const ushort* src;
            if (!ROOTX || kc < SROW)
                src = A + (size_t)grow * AS + kc + (bs >> 1);
            else
                src = xroot + (size_t)grow * IN_C + (kc - SROW) + (bs >> 1);
            GLOAD_LDS16(src, &As[(size_t)buf * 4096 + (L >> 1)]);
        }
    };

    STAGE(0, 0);
    __syncthreads();

#pragma unroll
    for (int t = 0; t < NTILE; ++t) {
        const int kc  = t * BK;
        const int buf = t & 1;

        // B fragments first (so vmcnt wait on B doesn't drain the stage)
        bf16x8 bB[2][NT];
#pragma unroll
        for (int kk = 0; kk < 2; ++kk)
#pragma unroll
            for (int nt = 0; nt < NT; ++nt)
                bB[kk][nt] = *(const bf16x8*)(
                    Wt + (size_t)(colBase + nt * 16 + l15) * K + kc + kk * 32 + lg * 8);

        // prefetch next tile into the other buffer
        if (t + 1 < NTILE) STAGE(buf ^ 1, t + 1);

        // A fragments from LDS (swizzled read)
        bf16x8 aF[2][2];
#pragma unroll
        for (int mt = 0; mt < 2; ++mt)
#pragma unroll
            for (int kk = 0; kk < 2; ++kk) {
                int row = wm * 32 + mt * 16 + l15;
                int kb  = kk * 64 + lg * 16;
                aF[mt][kk] = *(const bf16x8*)&As[
                    (size_t)buf * 4096 + row * 64 + ((kb ^ ((row & 7) << 4)) >> 1)];
            }

#pragma unroll
        for (int kk = 0; kk < 2; ++kk)
#pragma unroll
            for (int nt = 0; nt < NT; ++nt)
#pragma unroll
                for (int mt = 0; mt < 2; ++mt)
                    acc[mt][nt] = __builtin_amdgcn_mfma_f32_16x16x32_bf16(
                        aF[mt][kk], bB[kk][nt], acc[mt][nt], 0, 0, 0);

        __syncthreads();
    }

#pragma unroll
    for (int nt = 0; nt < NT; ++nt) {
        int n = colBase + nt * 16 + l15;
        float bv = bias ? bias[n] : 0.f;
#pragma unroll
        for (int mt = 0; mt < 2; ++mt) {
#pragma unroll
            for (int q = 0; q < 4; ++q) {
                int m = rowBase + wm * 32 + mt * 16 + lg * 4 + q;
                if (m < M) {
                    float v = acc[mt][nt][q] + bv;
                    size_t off = (size_t)m * OC + n;
                    if (OUT_BF16) ((ushort*)Cout)[off] = f2bf(v);
                    else          ((float*)Cout)[off]  = v;
                }
            }
        }
    }
}

// ---------------------------------------------------------------------------
// Bucketed CSR build.
__global__ __launch_bounds__(256) void bs0_k(const int* __restrict__ dstA,
                                             int* __restrict__ bcnt) {
    __shared__ int h[NBKT];
    int t = threadIdx.x;
    if (t < NBKT) h[t] = 0;
    __syncthreads();
    int e0 = blockIdx.x * CHUNK;
    int n = EE - e0; if (n > CHUNK) n = CHUNK;
    for (int i = t; i < n; i += 256)
        atomicAdd(&h[dstA[e0 + i] >> BSH], 1);
    __syncthreads();
    if (t < NBKT && h[t]) atomicAdd(&bcnt[t], h[t]);
}

__global__ void bscan_k(const int* __restrict__ bcnt, int* __restrict__ bbase,
                        int* __restrict__ bcur) {
    if (threadIdx.x == 0) {
        int run = 0;
        for (int i = 0; i < NBKT; ++i) { bbase[i] = run; bcur[i] = run; run += bcnt[i]; }
    }
}

// bs1: multi-split edges into bucket-contiguous (src, seg) payload with dense
// per-(block,bucket) runs; fused per-segment count. LDS-staged (17KB).
__global__ __launch_bounds__(256) void bs1_k(const int* __restrict__ srcA,
                                             const int* __restrict__ dstA,
                                             const int* __restrict__ et,
                                             int* __restrict__ bcur,
                                             int* __restrict__ bsrc,
                                             int* __restrict__ bseg,
                                             int* __restrict__ cnt) {
    __shared__ int h[NBKT], cur[NBKT], boff[NBKT];
    __shared__ int lseg[CHUNK];
    __shared__ int lsrc[CHUNK];
    int t = threadIdx.x;
    if (t < NBKT) { h[t] = 0; cur[t] = 0; }
    __syncthreads();
    int e0 = blockIdx.x * CHUNK;
    int n = EE - e0; if (n > CHUNK) n = CHUNK;
    for (int i = t; i < n; i += 256) {
        int e = e0 + i;
        int d = dstA[e];
        int s2 = d * 4 + et[e];
        lseg[i] = s2;
        lsrc[i] = srcA[e];
        atomicAdd(&h[d >> BSH], 1);
    }
    __syncthreads();
    if (t < NBKT && h[t]) boff[t] = atomicAdd(&bcur[t], h[t]);
    __syncthreads();
    for (int i = t; i < n; i += 256) {
        int s2 = lseg[i];
        int b = s2 >> (BSH + 2);
        int slot = atomicAdd(&cur[b], 1);
        int pos = boff[b] + slot;
        bsrc[pos] = lsrc[i];
        bseg[pos] = s2;
        atomicAdd(&cnt[s2], 1);
    }
}

// ---------------------------------------------------------------------------
// Segment-offset scan (counts -> exclusive base)
#define SCAN_B 256
#define SCAN_I 8
#define SCAN_T (SCAN_B * SCAN_I)   // 2048 elems per block

__global__ void scan1_k(const int* __restrict__ in, int* __restrict__ out,
                        int* __restrict__ bsum, int n) {
    __shared__ int sm[SCAN_B];
    int b = blockIdx.x;
    int t = threadIdx.x;
    int basei = b * SCAN_T + t * SCAN_I;
    int v[SCAN_I]; int s = 0;
#pragma unroll
    for (int i = 0; i < SCAN_I; ++i) {
        int idx = basei + i;
        v[i] = (idx < n) ? in[idx] : 0;
        s += v[i];
    }
    sm[t] = s; __syncthreads();
    for (int off = 1; off < SCAN_B; off <<= 1) {
        int x = (t >= off) ? sm[t - off] : 0;
        __syncthreads();
        sm[t] += x;
        __syncthreads();
    }
    int run = (t > 0) ? sm[t - 1] : 0;
    if (t == SCAN_B - 1) bsum[b] = sm[t];
#pragma unroll
    for (int i = 0; i < SCAN_I; ++i) {
        int idx = basei + i;
        if (idx < n) out[idx] = run;
        run += v[i];
    }
}

__global__ void scan2_k(int* __restrict__ bsum, int nb) {
    __shared__ int sm[256];
    int t = threadIdx.x;
    int v = (t < nb) ? bsum[t] : 0;
    sm[t] = v; __syncthreads();
    for (int off = 1; off < 256; off <<= 1) {
        int x = (t >= off) ? sm[t - off] : 0;
        __syncthreads();
        sm[t] += x;
        __syncthreads();
    }
    if (t < nb) bsum[t] = sm[t] - v;
}

__global__ void scan3inv_k(int* __restrict__ base, const int* __restrict__ bsum,
                           const int* __restrict__ cnt, float* __restrict__ inv,
                           int* __restrict__ cursor, int n) {
    int i = blockIdx.x * 256 + threadIdx.x;
    if (i < n) {
        int b = base[i] + bsum[i / SCAN_T];
        base[i] = b;
        cursor[i] = b;
        inv[i] = 1.0f / fmaxf((float)cnt[i], 1.0f);
    }
}

__global__ __launch_bounds__(256) void fill2_k(const int* __restrict__ bsrc,
                                               const int* __restrict__ bseg,
                                               const int* __restrict__ bbase,
                                               const int* __restrict__ bcnt,
                                               int* __restrict__ cursor,
                                               int* __restrict__ sorted) {
    int b   = blockIdx.x & (NBKT - 1);
    int cwb = blockIdx.x >> 6;
    int s = bbase[b] + cwb * FCHUNK;
    int e = bbase[b] + bcnt[b];
    if (e > s + FCHUNK) e = s + FCHUNK;
    for (int i = s + (int)threadIdx.x; i < e; i += 256) {
        int seg = bseg[i];
        int pos = atomicAdd(&cursor[seg], 1);
        sorted[pos] = bsrc[i];
    }
}

// ---------------------------------------------------------------------------
// Aggregate x rows per (relation, dst) into S (bf16, SROW=512 cols):
// S[d][r*128+c] = inv[d*4+r] * sum_{e in seg(d,r)} x[src_e][c]
// One wave per dst; 4 relations advance in lockstep (R10-proven version).
__global__ __launch_bounds__(256) void gatherS_k(
    const ushort* __restrict__ x, const int* __restrict__ sorted,
    const int* __restrict__ base, const int* __restrict__ cnt,
    const float* __restrict__ inv, ushort* __restrict__ S)
{
    int d = (blockIdx.x * 256 + threadIdx.x) >> 6;
    int lane = threadIdx.x & 63;
    if (d >= NN) return;
    const uint4* xp = (const uint4*)x;   // 16 uint4 per 128-col row
    uint4* Sp = (uint4*)S;               // 64 uint4 per 512-col row
    const int slot = lane >> 4;          // 0..3
    const int cg   = lane & 15;          // uint4 index within row

    int4   b4 = ((const int4*)base)[d];
    int4   c4 = ((const int4*)cnt)[d];
    float4 w4 = ((const float4*)inv)[d];
    const int off[4]  = {0, b4.y - b4.x, b4.z - b4.x, b4.w - b4.x};
    const int cnts[4] = {c4.x, c4.y, c4.z, c4.w};
    const float wts[4] = {w4.x, w4.y, w4.z, w4.w};
    const int tot = (b4.w + c4.w) - b4.x;

    f32x2 acc[4][4];
#pragma unroll
    for (int r = 0; r < 4; ++r)
#pragma unroll
        for (int t = 0; t < 4; ++t) acc[r][t] = (f32x2){0.f, 0.f};

    if (tot <= 64) {
        int idx = 0;
        if (lane < tot) idx = sorted[b4.x + lane];
        int maxn = max(max(cnts[0], cnts[1]), max(cnts[2], cnts[3]));
        for (int j = 0; j < maxn; j += 4) {
            int e = j + slot;
#pragma unroll
            for (int r = 0; r < 4; ++r) {
                int src = __shfl(idx, off[r] + e);
                if (e < cnts[r]) {
                    uint4 v = xp[(size_t)src * 16 + cg];
                    acc[r][0] += up2(v.x);
                    acc[r][1] += up2(v.y);
                    acc[r][2] += up2(v.z);
                    acc[r][3] += up2(v.w);
                }
            }
        }
    } else {
        // rare fallback: per-segment chunked processing
#pragma unroll
        for (int r = 0; r < 4; ++r) {
            int s0 = b4.x + off[r];
            int s1 = s0 + cnts[r];
            for (int i0 = s0; i0 < s1; i0 += 64) {
                int n = s1 - i0; if (n > 64) n = 64;
                int idx = 0;
                if (lane < n) idx = sorted[i0 + lane];
                for (int j = 0; j < n; j += 4) {
                    int e = j + slot;
                    int src = __shfl(idx, e);
                    if (e < n) {
                        uint4 v = xp[(size_t)src * 16 + cg];
                        acc[r][0] += up2(v.x);
                        acc[r][1] += up2(v.y);
                        acc[r][2] += up2(v.z);
                        acc[r][3] += up2(v.w);
                    }
                }
            }
        }
    }

#pragma unroll
    for (int r = 0; r < 4; ++r) {
        float wt = wts[r];
#pragma unroll
        for (int t = 0; t < 4; ++t) {
            acc[r][t].x += __shfl_xor(acc[r][t].x, 16);
            acc[r][t].y += __shfl_xor(acc[r][t].y, 16);
            acc[r][t].x += __shfl_xor(acc[r][t].x, 32);
            acc[r][t].y += __shfl_xor(acc[r][t].y, 32);
        }
        if (slot == 0) {
            uint4 o;
            o.x = pack2bf(acc[r][0].x * wt, acc[r][0].y * wt);
            o.y = pack2bf(acc[r][1].x * wt, acc[r][1].y * wt);
            o.z = pack2bf(acc[r][2].x * wt, acc[r][2].y * wt);
            o.w = pack2bf(acc[r][3].x * wt, acc[r][3].y * wt);
            Sp[(size_t)d * 64 + r * 16 + cg] = o;
        }
    }
}

// ---------------------------------------------------------------------------
extern "C" void kernel_launch(void* const* d_in, const int* in_sizes, int n_in,
                              void* d_out, int out_size, void* d_ws, size_t ws_size,
                              hipStream_t stream) {
    const float* x_mirna = (const float*)d_in[0];
    const float* x_gene  = (const float*)d_in[1];
    const int*   eidx    = (const int*)d_in[2];
    const int*   etype   = (const int*)d_in[3];
    const float* lin_w_m = (const float*)d_in[4];
    const float* lin_b_m = (const float*)d_in[5];
    const float* lin_w_g = (const float*)d_in[6];
    const float* lin_b_g = (const float*)d_in[7];
    const float* comp1   = (const float*)d_in[8];
    const float* basis1  = (const float*)d_in[9];
    const float* root1   = (const float*)d_in[10];
    const float* bias1   = (const float*)d_in[11];
    const float* comp2   = (const float*)d_in[12];
    const float* basis2  = (const float*)d_in[13];
    const float* root2   = (const float*)d_in[14];
    const float* bias2   = (const float*)d_in[15];

    const int* srcA = eidx;
    const int* dstA = eidx + EE;

    // workspace layout (bytes)
    char* p = (char*)d_ws;
    ushort* xmbf = (ushort*)p; p += (size_t)NUM_MIRNA * 256 * 2;
    ushort* xgbf = (ushort*)p; p += (size_t)NUM_GENE * 512 * 2;
    ushort* x0bf = (ushort*)p; p += (size_t)NN * IN_C * 2;
    ushort* x1bf = (ushort*)p; p += (size_t)NN * HIDC * 2;
    ushort* S    = (ushort*)p; p += (size_t)NN * SROW * 2;      // 51.2 MB
    ushort* Wtm  = (ushort*)p; p += (size_t)IN_C * 256 * 2;
    ushort* Wtg  = (ushort*)p; p += (size_t)IN_C * 512 * 2;
    ushort* Wt1s = (ushort*)p; p += (size_t)HIDC * KFUSE * 2;
    ushort* Wt2s = (ushort*)p; p += (size_t)OUTC * KFUSE * 2;
    float* inv   = (float*)p;  p += (size_t)NSEG * 4;
    int* cnt     = (int*)p;    p += (size_t)NSEG * 4;
    int* bcnt    = (int*)p;    p += NBKT * 4;                   // adjacent to cnt
    int* base    = (int*)p;    p += (size_t)NSEG * 4;
    int* cursor  = (int*)p;    p += (size_t)NSEG * 4;
    int* bsum    = (int*)p;    p += 1024;
    int* bbase   = (int*)p;    p += NBKT * 4;
    int* bcur    = (int*)p;    p += NBKT * 4;
    int* sorted  = (int*)p;    p += (size_t)EE * 4;
    int* bsrc    = (int*)p;    p += (size_t)EE * 4;
    int* bseg    = (int*)p;    p += (size_t)EE * 4;

    float* outp = (float*)d_out;

    hipMemsetAsync(cnt, 0, (size_t)(NSEG + NBKT) * sizeof(int), stream);

    // bf16 converts of inputs
    cvt_k<<<(NUM_MIRNA * 256 / 4 + 255) / 256, 256, 0, stream>>>(x_mirna, xmbf, NUM_MIRNA * 256 / 4);
    cvt_k<<<(NUM_GENE * 512 / 4 + 255) / 256, 256, 0, stream>>>(x_gene, xgbf, NUM_GENE * 512 / 4);

    // packed transposed weights
    tcast_k<<<(256 * IN_C + 255) / 256, 256, 0, stream>>>(lin_w_m, Wtm, 256, IN_C);
    tcast_k<<<(512 * IN_C + 255) / 256, 256, 0, stream>>>(lin_w_g, Wtg, 512, IN_C);
    buildW_k<<<(HIDC * KFUSE + 255) / 256, 256, 0, stream>>>(comp1, basis1, root1, Wt1s, HIDC);
    buildW_k<<<(OUTC * KFUSE + 255) / 256, 256, 0, stream>>>(comp2, basis2, root2, Wt2s, OUTC);

    // bucketed CSR build
    bs0_k<<<NCHUNK, 256, 0, stream>>>(dstA, bcnt);
    bscan_k<<<1, 64, 0, stream>>>(bcnt, bbase, bcur);
    bs1_k<<<NCHUNK, 256, 0, stream>>>(srcA, dstA, etype, bcur, bsrc, bseg, cnt);
    int nb = (NSEG + SCAN_T - 1) / SCAN_T;
    scan1_k<<<nb, SCAN_B, 0, stream>>>(cnt, base, bsum, NSEG);
    scan2_k<<<1, 256, 0, stream>>>(bsum, nb);
    scan3inv_k<<<(NSEG + 255) / 256, 256, 0, stream>>>(base, bsum, cnt, inv, cursor, NSEG);
    fill2_k<<<NBKT * CPB, 256, 0, stream>>>(bsrc, bseg, bbase, bcnt, cursor, sorted);

    // input projections -> x0bf (staged GEMMs, bf16 A)
    sgemm_k<4, 256, true, false><<<dim3((NUM_MIRNA + 63) / 64), 256, 0, stream>>>(
        xmbf, nullptr, Wtm, lin_b_m, x0bf, NUM_MIRNA);
    sgemm_k<4, 512, true, false><<<dim3((NUM_GENE + 63) / 64), 256, 0, stream>>>(
        xgbf, nullptr, Wtg, lin_b_g, x0bf + (size_t)NUM_MIRNA * IN_C, NUM_GENE);

    // layer 1: aggregate x0 -> S, then fused [rel GEMMs + root + bias]
    gatherS_k<<<(NN * 64 + 255) / 256, 256, 0, stream>>>(x0bf, sorted, base, cnt, inv, S);
    sgemm_k<4, KFUSE, true, true><<<dim3((NN + 63) / 64), 256, 0, stream>>>(
        S, x0bf, Wt1s, bias1, x1bf, NN);

    // layer 2: aggregate x1 -> S, fused GEMM -> out (fp32)
    gatherS_k<<<(NN * 64 + 255) / 256, 256, 0, stream>>>(x1bf, sorted, base, cnt, inv, S);
    sgemm_k<2, KFUSE, false, true><<<dim3((NN + 63) / 64), 256, 0, stream>>>(
        S, x1bf, Wt2s, bias2, outp, NN);
}

// Round 13
// 287.547 us; speedup vs baseline: 1.4119x; 1.2717x over previous
//
#include <hip/hip_runtime.h>
#include <hip/hip_bf16.h>

// Problem constants (match reference)
#define NUM_MIRNA 20000
#define NUM_GENE  30000
#define NN        50000      // total nodes
#define RR        4          // relations
#define EE        1000000    // edges
#define IN_C      128
#define HIDC      128
#define OUTC      64
#define NBASIS    10
#define NSEG      (RR * NN)  // 200000, seg = dst*4 + r
#define NSEGP     200704     // padded to 196*1024 for sortbkt block writes
#define KFUSE     640        // 4*128 aggregated blocks + 128 root block
#define SROW      512        // S row length (bf16 cols) — root block read from x

#define NBKT   256           // dst-range buckets (196 used)
#define BSH    8             // bucket = dst >> 8  (256 dsts -> 1024 segs each)
#define NBKTU  ((NN + 255) >> 8)            // 196 active buckets
#define CHUNK  4096          // bs0/bs1 work per block
#define NCHUNK ((EE + CHUNK - 1) / CHUNK)   // 245

typedef __attribute__((ext_vector_type(8))) short bf16x8;
typedef __attribute__((ext_vector_type(4))) float f32x4;
typedef __attribute__((ext_vector_type(2))) float f32x2;

__device__ inline ushort f2bf(float x) {
    uint u = __float_as_uint(x);
    uint r = u + 0x7fffu + ((u >> 16) & 1u);
    return (ushort)(r >> 16);
}
__device__ inline float bf2f(ushort b) {
    return __uint_as_float((uint)b << 16);
}
__device__ inline uint pack2bf(float lo, float hi) {
    return (uint)f2bf(lo) | ((uint)f2bf(hi) << 16);
}
__device__ inline f32x2 up2(uint u) {   // unpack 2 bf16 -> f32x2 (lo, hi)
    return (f32x2){__uint_as_float(u << 16), __uint_as_float(u & 0xffff0000u)};
}

// async global->LDS, 16 bytes per lane (wave-linear LDS dest)
#define GLOAD_LDS16(gsrc, ldst)                                                \
    __builtin_amdgcn_global_load_lds(                                          \
        (const __attribute__((address_space(1))) void*)(gsrc),                 \
        (__attribute__((address_space(3))) void*)(ldst), 16, 0, 0)

// ---------------------------------------------------------------------------
// fp32 -> bf16 (4 elems/thread)
__global__ void cvt_k(const float* __restrict__ in, ushort* __restrict__ out, int n4) {
    int i = blockIdx.x * 256 + threadIdx.x;
    if (i >= n4) return;
    float4 v = ((const float4*)in)[i];
    ushort4 o;
    o.x = f2bf(v.x); o.y = f2bf(v.y); o.z = f2bf(v.z); o.w = f2bf(v.w);
    ((ushort4*)out)[i] = o;
}

// transpose+cast: Wt[o][k] = bf16(W[k][o]);  W: [K][OC]  (input projections)
__global__ void tcast_k(const float* __restrict__ W, ushort* __restrict__ Wt,
                        int K, int OC) {
    int idx = blockIdx.x * 256 + threadIdx.x;
    if (idx >= K * OC) return;
    int o = idx / K, k = idx % K;
    Wt[idx] = f2bf(W[(size_t)k * OC + o]);
}

// Build stacked transposed fused weight: Wt[o][k], k in [0,640)
__global__ void buildW_k(const float* __restrict__ comp, const float* __restrict__ basis,
                         const float* __restrict__ root, ushort* __restrict__ Wt, int O) {
    int idx = blockIdx.x * 256 + threadIdx.x;
    if (idx >= O * KFUSE) return;
    int o = idx / KFUSE, k = idx % KFUSE;
    float acc;
    if (k < 512) {
        int r = k >> 7, i = k & 127;
        acc = 0.f;
#pragma unroll
        for (int b = 0; b < NBASIS; ++b)
            acc += comp[r * NBASIS + b] * basis[((size_t)b * 128 + i) * O + o];
    } else {
        acc = root[(size_t)(k - 512) * O + o];
    }
    Wt[idx] = f2bf(acc);
}

// ---------------------------------------------------------------------------
// Staged MFMA bf16 GEMM: C[M][OC] = A[M][K] @ Wt[OC][K]^T (+bias)
// 2-phase double-buffered LDS pipeline with global_load_lds + XOR swizzle.
template <int NT, int K, bool OUT_BF16, bool ROOTX>
__global__ __launch_bounds__(256) void sgemm_k(
    const ushort* __restrict__ A, const ushort* __restrict__ xroot,
    const ushort* __restrict__ Wt, const float* __restrict__ bias,
    void* __restrict__ Cout, int M)
{
    constexpr int OC = 2 * NT * 16;
    constexpr int BK = 64;
    constexpr int NTILE = K / BK;
    constexpr int AS = ROOTX ? SROW : K;

    __shared__ __align__(16) ushort As[2 * 4096];   // 2 x (64x64) bf16 = 16KB

    const int tid  = threadIdx.x;
    const int lane = tid & 63;
    const int wid  = tid >> 6;
    const int wm   = wid >> 1;
    const int wn   = wid & 1;
    const int l15  = lane & 15;
    const int lg   = lane >> 4;
    const int rowBase = blockIdx.x * 64;
    const int colBase = wn * NT * 16;

    f32x4 acc[2][NT];
#pragma unroll
    for (int mt = 0; mt < 2; ++mt)
#pragma unroll
        for (int nt = 0; nt < NT; ++nt)
            acc[mt][nt] = (f32x4){0.f, 0.f, 0.f, 0.f};

    auto STAGE = [&](int buf, int t) {
        const int kc = t * BK;
#pragma unroll
        for (int i = 0; i < 2; ++i) {
            int L   = i * 4096 + tid * 16;      // byte offset within 8KB tile
            int row = L >> 7;                    // 0..63
            int bs  = (L & 127) ^ ((row & 7) << 4);  // pre-swizzled src byte
            int grow = rowBase + row; if (grow >= M) grow = M - 1;
            const ushort* src;
            if (!ROOTX || kc < SROW)
                src = A + (size_t)grow * AS + kc + (bs >> 1);
            else
                src = xroot + (size_t)grow * IN_C + (kc - SROW) + (bs >> 1);
            GLOAD_LDS16(src, &As[(size_t)buf * 4096 + (L >> 1)]);
        }
    };

    STAGE(0, 0);
    __syncthreads();

#pragma unroll
    for (int t = 0; t < NTILE; ++t) {
        const int kc  = t * BK;
        const int buf = t & 1;

        // B fragments first (so vmcnt wait on B doesn't drain the stage)
        bf16x8 bB[2][NT];
#pragma unroll
        for (int kk = 0; kk < 2; ++kk)
#pragma unroll
            for (int nt = 0; nt < NT; ++nt)
                bB[kk][nt] = *(const bf16x8*)(
                    Wt + (size_t)(colBase + nt * 16 + l15) * K + kc + kk * 32 + lg * 8);

        // prefetch next tile into the other buffer
        if (t + 1 < NTILE) STAGE(buf ^ 1, t + 1);

        // A fragments from LDS (swizzled read)
        bf16x8 aF[2][2];
#pragma unroll
        for (int mt = 0; mt < 2; ++mt)
#pragma unroll
            for (int kk = 0; kk < 2; ++kk) {
                int row = wm * 32 + mt * 16 + l15;
                int kb  = kk * 64 + lg * 16;
                aF[mt][kk] = *(const bf16x8*)&As[
                    (size_t)buf * 4096 + row * 64 + ((kb ^ ((row & 7) << 4)) >> 1)];
            }

#pragma unroll
        for (int kk = 0; kk < 2; ++kk)
#pragma unroll
            for (int nt = 0; nt < NT; ++nt)
#pragma unroll
                for (int mt = 0; mt < 2; ++mt)
                    acc[mt][nt] = __builtin_amdgcn_mfma_f32_16x16x32_bf16(
                        aF[mt][kk], bB[kk][nt], acc[mt][nt], 0, 0, 0);

        __syncthreads();
    }

#pragma unroll
    for (int nt = 0; nt < NT; ++nt) {
        int n = colBase + nt * 16 + l15;
        float bv = bias ? bias[n] : 0.f;
#pragma unroll
        for (int mt = 0; mt < 2; ++mt) {
#pragma unroll
            for (int q = 0; q < 4; ++q) {
                int m = rowBase + wm * 32 + mt * 16 + lg * 4 + q;
                if (m < M) {
                    float v = acc[mt][nt][q] + bv;
                    size_t off = (size_t)m * OC + n;
                    if (OUT_BF16) ((ushort*)Cout)[off] = f2bf(v);
                    else          ((float*)Cout)[off]  = v;
                }
            }
        }
    }
}

// ---------------------------------------------------------------------------
// Bucketed CSR build.
__global__ __launch_bounds__(256) void bs0_k(const int* __restrict__ dstA,
                                             int* __restrict__ bcnt) {
    __shared__ int h[NBKT];
    int t = threadIdx.x;
    h[t] = 0;
    __syncthreads();
    int e0 = blockIdx.x * CHUNK;
    int n = EE - e0; if (n > CHUNK) n = CHUNK;
    for (int i = t; i < n; i += 256)
        atomicAdd(&h[dstA[e0 + i] >> BSH], 1);
    __syncthreads();
    if (h[t]) atomicAdd(&bcnt[t], h[t]);
}

// parallel exclusive scan of 256 bucket counts -> bbase, bcur
__global__ void bscan_k(const int* __restrict__ bcnt, int* __restrict__ bbase,
                        int* __restrict__ bcur) {
    __shared__ int sm[NBKT];
    int t = threadIdx.x;
    int v = bcnt[t];
    sm[t] = v; __syncthreads();
    for (int off = 1; off < NBKT; off <<= 1) {
        int x = (t >= off) ? sm[t - off] : 0;
        __syncthreads();
        sm[t] += x;
        __syncthreads();
    }
    int ex = sm[t] - v;
    bbase[t] = ex;
    bcur[t]  = ex;
}

// bs1: multi-split edges into bucket-contiguous packed (src,seg) payload.
// NO global per-seg atomics (counts computed later in sortbkt from payload).
__global__ __launch_bounds__(256) void bs1_k(const int* __restrict__ srcA,
                                             const int* __restrict__ dstA,
                                             const int* __restrict__ et,
                                             int* __restrict__ bcur,
                                             uint2* __restrict__ bpay) {
    __shared__ int h[NBKT], cur[NBKT], boff[NBKT];
    __shared__ int lseg[CHUNK];
    __shared__ int lsrc[CHUNK];
    int t = threadIdx.x;
    h[t] = 0; cur[t] = 0;
    __syncthreads();
    int e0 = blockIdx.x * CHUNK;
    int n = EE - e0; if (n > CHUNK) n = CHUNK;
    for (int i = t; i < n; i += 256) {
        int e = e0 + i;
        int d = dstA[e];
        int s2 = d * 4 + et[e];
        lseg[i] = s2;
        lsrc[i] = srcA[e];
        atomicAdd(&h[d >> BSH], 1);
    }
    __syncthreads();
    if (h[t]) boff[t] = atomicAdd(&bcur[t], h[t]);
    __syncthreads();
    for (int i = t; i < n; i += 256) {
        int s2 = lseg[i];
        int b = s2 >> (BSH + 2);
        int slot = atomicAdd(&cur[b], 1);
        bpay[boff[b] + slot] = make_uint2((uint)lsrc[i], (uint)s2);
    }
}

// ---------------------------------------------------------------------------
// sortbkt: per-bucket counting sort + CSR metadata, one block per bucket.
// LDS histogram over the bucket's 1024 segs -> local scan -> coalesced
// cnt/base/inv writes -> LDS-cursor scatter of sorted (bucket-local window).
__global__ __launch_bounds__(256) void sortbkt_k(
    const uint2* __restrict__ bpay, const int* __restrict__ bbase,
    const int* __restrict__ bcnt, int* __restrict__ sorted,
    int* __restrict__ cnt, int* __restrict__ base, float* __restrict__ inv)
{
    __shared__ int hist[1024];
    __shared__ int tsum[256];
    const int b = blockIdx.x;
    const int t = threadIdx.x;
    const int segbase = b << 10;

#pragma unroll
    for (int i = 0; i < 4; ++i) hist[t + i * 256] = 0;
    __syncthreads();

    const int e0 = bbase[b];
    const int n  = bcnt[b];
    for (int i = t; i < n; i += 256)
        atomicAdd(&hist[(int)bpay[e0 + i].y - segbase], 1);
    __syncthreads();

    // local counts for this thread's 4 consecutive bins
    int h0 = hist[t * 4], h1 = hist[t * 4 + 1], h2 = hist[t * 4 + 2], h3 = hist[t * 4 + 3];
    int s = h0 + h1 + h2 + h3;
    tsum[t] = s; __syncthreads();
    for (int off = 1; off < 256; off <<= 1) {
        int x = (t >= off) ? tsum[t - off] : 0;
        __syncthreads();
        tsum[t] += x;
        __syncthreads();
    }
    int run = (t > 0) ? tsum[t - 1] : 0;   // exclusive base of this thread's bins
    int b0 = run, b1 = run + h0, b2 = b1 + h1, b3 = b2 + h2;

    // coalesced metadata writes (int4/float4 per thread)
    ((int4*)cnt)[(segbase >> 2) + t]  = make_int4(h0, h1, h2, h3);
    ((int4*)base)[(segbase >> 2) + t] = make_int4(e0 + b0, e0 + b1, e0 + b2, e0 + b3);
    ((float4*)inv)[(segbase >> 2) + t] = make_float4(
        1.0f / fmaxf((float)h0, 1.0f), 1.0f / fmaxf((float)h1, 1.0f),
        1.0f / fmaxf((float)h2, 1.0f), 1.0f / fmaxf((float)h3, 1.0f));

    // hist becomes the local cursor
    hist[t * 4] = b0; hist[t * 4 + 1] = b1; hist[t * 4 + 2] = b2; hist[t * 4 + 3] = b3;
    __syncthreads();

    for (int i = t; i < n; i += 256) {
        uint2 pr = bpay[e0 + i];
        int pos = atomicAdd(&hist[(int)pr.y - segbase], 1);
        sorted[e0 + pos] = (int)pr.x;
    }
}

// ---------------------------------------------------------------------------
// Aggregate x rows per (relation, dst) into S (bf16, SROW=512 cols):
// S[d][r*128+c] = inv[d*4+r] * sum_{e in seg(d,r)} x[src_e][c]
// One wave per dst; 4 relations advance in lockstep (R10-proven version).
__global__ __launch_bounds__(256) void gatherS_k(
    const ushort* __restrict__ x, const int* __restrict__ sorted,
    const int* __restrict__ base, const int* __restrict__ cnt,
    const float* __restrict__ inv, ushort* __restrict__ S)
{
    int d = (blockIdx.x * 256 + threadIdx.x) >> 6;
    int lane = threadIdx.x & 63;
    if (d >= NN) return;
    const uint4* xp = (const uint4*)x;   // 16 uint4 per 128-col row
    uint4* Sp = (uint4*)S;               // 64 uint4 per 512-col row
    const int slot = lane >> 4;          // 0..3
    const int cg   = lane & 15;          // uint4 index within row

    int4   b4 = ((const int4*)base)[d];
    int4   c4 = ((const int4*)cnt)[d];
    float4 w4 = ((const float4*)inv)[d];
    const int off[4]  = {0, b4.y - b4.x, b4.z - b4.x, b4.w - b4.x};
    const int cnts[4] = {c4.x, c4.y, c4.z, c4.w};
    const float wts[4] = {w4.x, w4.y, w4.z, w4.w};
    const int tot = (b4.w + c4.w) - b4.x;

    f32x2 acc[4][4];
#pragma unroll
    for (int r = 0; r < 4; ++r)
#pragma unroll
        for (int t = 0; t < 4; ++t) acc[r][t] = (f32x2){0.f, 0.f};

    if (tot <= 64) {
        int idx = 0;
        if (lane < tot) idx = sorted[b4.x + lane];
        int maxn = max(max(cnts[0], cnts[1]), max(cnts[2], cnts[3]));
        for (int j = 0; j < maxn; j += 4) {
            int e = j + slot;
#pragma unroll
            for (int r = 0; r < 4; ++r) {
                int src = __shfl(idx, off[r] + e);
                if (e < cnts[r]) {
                    uint4 v = xp[(size_t)src * 16 + cg];
                    acc[r][0] += up2(v.x);
                    acc[r][1] += up2(v.y);
                    acc[r][2] += up2(v.z);
                    acc[r][3] += up2(v.w);
                }
            }
        }
    } else {
        // rare fallback: per-segment chunked processing
#pragma unroll
        for (int r = 0; r < 4; ++r) {
            int s0 = b4.x + off[r];
            int s1 = s0 + cnts[r];
            for (int i0 = s0; i0 < s1; i0 += 64) {
                int n = s1 - i0; if (n > 64) n = 64;
                int idx = 0;
                if (lane < n) idx = sorted[i0 + lane];
                for (int j = 0; j < n; j += 4) {
                    int e = j + slot;
                    int src = __shfl(idx, e);
                    if (e < n) {
                        uint4 v = xp[(size_t)src * 16 + cg];
                        acc[r][0] += up2(v.x);
                        acc[r][1] += up2(v.y);
                        acc[r][2] += up2(v.z);
                        acc[r][3] += up2(v.w);
                    }
                }
            }
        }
    }

#pragma unroll
    for (int r = 0; r < 4; ++r) {
        float wt = wts[r];
#pragma unroll
        for (int t = 0; t < 4; ++t) {
            acc[r][t].x += __shfl_xor(acc[r][t].x, 16);
            acc[r][t].y += __shfl_xor(acc[r][t].y, 16);
            acc[r][t].x += __shfl_xor(acc[r][t].x, 32);
            acc[r][t].y += __shfl_xor(acc[r][t].y, 32);
        }
        if (slot == 0) {
            uint4 o;
            o.x = pack2bf(acc[r][0].x * wt, acc[r][0].y * wt);
            o.y = pack2bf(acc[r][1].x * wt, acc[r][1].y * wt);
            o.z = pack2bf(acc[r][2].x * wt, acc[r][2].y * wt);
            o.w = pack2bf(acc[r][3].x * wt, acc[r][3].y * wt);
            Sp[(size_t)d * 64 + r * 16 + cg] = o;
        }
    }
}

// ---------------------------------------------------------------------------
extern "C" void kernel_launch(void* const* d_in, const int* in_sizes, int n_in,
                              void* d_out, int out_size, void* d_ws, size_t ws_size,
                              hipStream_t stream) {
    const float* x_mirna = (const float*)d_in[0];
    const float* x_gene  = (const float*)d_in[1];
    const int*   eidx    = (const int*)d_in[2];
    const int*   etype   = (const int*)d_in[3];
    const float* lin_w_m = (const float*)d_in[4];
    const float* lin_b_m = (const float*)d_in[5];
    const float* lin_w_g = (const float*)d_in[6];
    const float* lin_b_g = (const float*)d_in[7];
    const float* comp1   = (const float*)d_in[8];
    const float* basis1  = (const float*)d_in[9];
    const float* root1   = (const float*)d_in[10];
    const float* bias1   = (const float*)d_in[11];
    const float* comp2   = (const float*)d_in[12];
    const float* basis2  = (const float*)d_in[13];
    const float* root2   = (const float*)d_in[14];
    const float* bias2   = (const float*)d_in[15];

    const int* srcA = eidx;
    const int* dstA = eidx + EE;

    // workspace layout (bytes)
    char* p = (char*)d_ws;
    ushort* xmbf = (ushort*)p; p += (size_t)NUM_MIRNA * 256 * 2;
    ushort* xgbf = (ushort*)p; p += (size_t)NUM_GENE * 512 * 2;
    ushort* x0bf = (ushort*)p; p += (size_t)NN * IN_C * 2;
    ushort* x1bf = (ushort*)p; p += (size_t)NN * HIDC * 2;
    ushort* S    = (ushort*)p; p += (size_t)NN * SROW * 2;      // 51.2 MB
    ushort* Wtm  = (ushort*)p; p += (size_t)IN_C * 256 * 2;
    ushort* Wtg  = (ushort*)p; p += (size_t)IN_C * 512 * 2;
    ushort* Wt1s = (ushort*)p; p += (size_t)HIDC * KFUSE * 2;
    ushort* Wt2s = (ushort*)p; p += (size_t)OUTC * KFUSE * 2;
    float* inv   = (float*)p;  p += (size_t)NSEGP * 4;
    int* cnt     = (int*)p;    p += (size_t)NSEGP * 4;
    int* base    = (int*)p;    p += (size_t)NSEGP * 4;
    int* bcnt    = (int*)p;    p += NBKT * 4;
    int* bbase   = (int*)p;    p += NBKT * 4;
    int* bcur    = (int*)p;    p += NBKT * 4;
    int* sorted  = (int*)p;    p += (size_t)EE * 4;
    uint2* bpay  = (uint2*)p;  p += (size_t)EE * 8;

    float* outp = (float*)d_out;

    hipMemsetAsync(bcnt, 0, NBKT * sizeof(int), stream);

    // bf16 converts of inputs
    cvt_k<<<(NUM_MIRNA * 256 / 4 + 255) / 256, 256, 0, stream>>>(x_mirna, xmbf, NUM_MIRNA * 256 / 4);
    cvt_k<<<(NUM_GENE * 512 / 4 + 255) / 256, 256, 0, stream>>>(x_gene, xgbf, NUM_GENE * 512 / 4);

    // packed transposed weights
    tcast_k<<<(256 * IN_C + 255) / 256, 256, 0, stream>>>(lin_w_m, Wtm, 256, IN_C);
    tcast_k<<<(512 * IN_C + 255) / 256, 256, 0, stream>>>(lin_w_g, Wtg, 512, IN_C);
    buildW_k<<<(HIDC * KFUSE + 255) / 256, 256, 0, stream>>>(comp1, basis1, root1, Wt1s, HIDC);
    buildW_k<<<(OUTC * KFUSE + 255) / 256, 256, 0, stream>>>(comp2, basis2, root2, Wt2s, OUTC);

    // bucketed CSR build: histogram -> scan -> partition -> per-bucket sort
    bs0_k<<<NCHUNK, 256, 0, stream>>>(dstA, bcnt);
    bscan_k<<<1, NBKT, 0, stream>>>(bcnt, bbase, bcur);
    bs1_k<<<NCHUNK, 256, 0, stream>>>(srcA, dstA, etype, bcur, bpay);
    sortbkt_k<<<NBKTU, 256, 0, stream>>>(bpay, bbase, bcnt, sorted, cnt, base, inv);

    // input projections -> x0bf (staged GEMMs, bf16 A)
    sgemm_k<4, 256, true, false><<<dim3((NUM_MIRNA + 63) / 64), 256, 0, stream>>>(
        xmbf, nullptr, Wtm, lin_b_m, x0bf, NUM_MIRNA);
    sgemm_k<4, 512, true, false><<<dim3((NUM_GENE + 63) / 64), 256, 0, stream>>>(
        xgbf, nullptr, Wtg, lin_b_g, x0bf + (size_t)NUM_MIRNA * IN_C, NUM_GENE);

    // layer 1: aggregate x0 -> S, then fused [rel GEMMs + root + bias]
    gatherS_k<<<(NN * 64 + 255) / 256, 256, 0, stream>>>(x0bf, sorted, base, cnt, inv, S);
    sgemm_k<4, KFUSE, true, true><<<dim3((NN + 63) / 64), 256, 0, stream>>>(
        S, x0bf, Wt1s, bias1, x1bf, NN);

    // layer 2: aggregate x1 -> S, fused GEMM -> out (fp32)
    gatherS_k<<<(NN * 64 + 255) / 256, 256, 0, stream>>>(x1bf, sorted, base, cnt, inv, S);
    sgemm_k<2, KFUSE, false, true><<<dim3((NN + 63) / 64), 256, 0, stream>>>(
        S, x1bf, Wt2s, bias2, outp, NN);
}